// Round 14
// baseline (1856.819 us; speedup 1.0000x reference)
//
#include <hip/hip_runtime.h>

#define T_STEPS 1000
#define NIN     128
#define NREC    512
#define NBATCH  64
#define ALPHA   0.2f

#define NSLICE  4          // blocks per batch element
#define SCOLS   128        // columns per slice (512/4)
#define NGRP    8          // k-groups per block (16 waves = 8 kgrp x 2 halves)
#define KPER    64         // k elements per k-group

// d_ws layout (bytes):
//   [0, 1MB)            W_eff (512x512 fp32)
//   [1MB, +512KB)       comm  (LLC slots): 2 parities x 64 x 512 u64 {tag,h}
//   [1.5MB, +512KB)     comm2 (L2 slots):  same layout, plain-store path
#define WS_W_OFF      0
#define WS_COMM_OFF   (1u << 20)
#define COMM_U64      (NBATCH * NREC)              // u64 elements per parity
#define COMM_BYTES    (2 * COMM_U64 * 8)           // 512 KB
#define WS_COMM2_OFF  (WS_COMM_OFF + COMM_BYTES)
#define WS_NEEDED_LLC (WS_COMM_OFF + COMM_BYTES)
#define WS_NEEDED_DUAL (WS_COMM2_OFF + COMM_BYTES)

// --- comm primitives (proven r10-r12) ------------------------------------
__device__ __forceinline__ unsigned long long ld_l2(
        const unsigned long long* p) {
    unsigned long long r;
    asm volatile("global_load_dwordx2 %0, %1, off sc0\n\t"
                 "s_waitcnt vmcnt(0)"
                 : "=v"(r) : "v"(p) : "memory");
    return r;
}
__device__ __forceinline__ void st_l2(unsigned long long* p,
                                      unsigned long long v) {
    asm volatile("global_store_dwordx2 %0, %1, off"
                 :: "v"(p), "v"(v) : "memory");
}
__device__ __forceinline__ unsigned long long ld_llc(
        const unsigned long long* p) {
    return __hip_atomic_load(p, __ATOMIC_RELAXED, __HIP_MEMORY_SCOPE_AGENT);
}
__device__ __forceinline__ void st_llc(unsigned long long* p,
                                       unsigned long long v) {
    __hip_atomic_store(p, v, __ATOMIC_RELAXED, __HIP_MEMORY_SCOPE_AGENT);
}
__device__ __forceinline__ int ld_lds_i32(const int* p) {
    return __hip_atomic_load(p, __ATOMIC_RELAXED, __HIP_MEMORY_SCOPE_WORKGROUP);
}

// ---------------------------------------------------------------------------
// W_eff[k][j] = ei[k] * w_rec[k][j] * autapse[k][j]
// ---------------------------------------------------------------------------
__global__ void weff_kernel(const float* __restrict__ w_rec,
                            const float* __restrict__ ei_mask,
                            const float* __restrict__ autapse,
                            float* __restrict__ w_eff) {
    int idx = blockIdx.x * blockDim.x + threadIdx.x;
    if (idx < NREC * NREC) {
        int row = idx >> 9;
        float ei = ei_mask[row * NREC + row];
        w_eff[idx] = ei * w_rec[idx] * autapse[idx];
    }
}

// ---------------------------------------------------------------------------
// inp_all[m][j] = sum_k x[m][k] * w_in[k][j] + b_rec[j]   (into d_out)
// ---------------------------------------------------------------------------
__global__ __launch_bounds__(1024) void gemm_in_kernel(
        const float* __restrict__ x,
        const float* __restrict__ w_in,
        const float* __restrict__ b_rec,
        float* __restrict__ io) {
    __shared__ float xs[32][NIN];

    const int tid = threadIdx.x;
    const int m0  = blockIdx.x * 32;

    {
        const float4* src = reinterpret_cast<const float4*>(x + (size_t)m0 * NIN);
        reinterpret_cast<float4*>(&xs[0][0])[tid] = src[tid];
    }
    __syncthreads();

    const int j0 = tid & 255;
    const int j1 = j0 + 256;
    const int rg = tid >> 8;

    float acc[8][2];
#pragma unroll
    for (int i = 0; i < 8; ++i) { acc[i][0] = 0.f; acc[i][1] = 0.f; }

#pragma unroll 4
    for (int k = 0; k < NIN; ++k) {
        float wv0 = w_in[k * NREC + j0];
        float wv1 = w_in[k * NREC + j1];
#pragma unroll
        for (int i = 0; i < 8; ++i) {
            float xv = xs[rg * 8 + i][k];
            acc[i][0] = fmaf(xv, wv0, acc[i][0]);
            acc[i][1] = fmaf(xv, wv1, acc[i][1]);
        }
    }

    const float br0 = b_rec[j0];
    const float br1 = b_rec[j1];
#pragma unroll
    for (int i = 0; i < 8; ++i) {
        size_t ro = (size_t)(m0 + rg * 8 + i) * NREC;
        io[ro + j0] = acc[i][0] + br0;
        io[ro + j1] = acc[i][1] + br1;
    }
}

// ---------------------------------------------------------------------------
// Cooperative recurrence, barrier-free with PER-WAVE partial slots (no
// shared accumulator, no re-initialization -> no lost-write window).
// 256 blocks: batch b (slices share bid%8 -> likely one XCD), slice s.
// 16 waves: k-group g=w>>1 (k in [64g,+64)), col-half c=w&1, col=c*64+ln.
// Lane holds Wr[u]=W[64g+u][s*128+col] (64 pinned regs).
// Per step t (parity p=t&1):
//   acquire h:  wave 4s: own hj regs. own-slice waves: spin monotone
//               hflag[p][g&1], read h_own[p]. remote: dual-path comm poll.
//   dot:        64 readlane + 64 fmac (VALU).
//   publish:    part[p][g][col] = partial; lgkm drain; ln0: wflag[p][w]=t.
//   leaders (waves 4s,4s+1; poll ONLY LDS -> safe to carry vmem prefetch):
//               issue io/noise row-(t+1) loads; spin until all wflag[p]>=t
//               (1 ds_read + __all per round); sum 8 slots + inp + noise;
//               update h; write h_own[p^1] + hflag[p^1]; publish {t+1,h}
//               dual-path; store io row t; retire prefetch into registers.
// Monotone flags only; parity-slot overwrites at t+2 are gated behind the
// leader's step-t reads via the tag chain (same proof as comm slots).
// ---------------------------------------------------------------------------
__global__ __launch_bounds__(1024, 4) void rnn_coop(
        const float* __restrict__ W,
        const float* __restrict__ noise,
        float* __restrict__ io,
        unsigned long long* __restrict__ comm,     // LLC slots
        unsigned long long* __restrict__ comm2) {  // L2 slots (may be null)
    __shared__ float h_own[2][SCOLS];              // [parity][col]
    __shared__ float part[2][NGRP][SCOLS];         // per-wave partial slots
    __shared__ int   wflag[2][16];                 // [parity][wave] = step
    __shared__ int   hflag[2][2];                  // [parity][col-half] = tag

    const int tid = threadIdx.x;
    const int bid = blockIdx.x;
    const int b   = (bid & 7) + 8 * (bid >> 5);    // slices of b share bid%8
    const int s   = (bid >> 3) & 3;
    const int w   = tid >> 6;              // wave 0..15
    const int ln  = tid & 63;
    const int g   = w >> 1;                // k-group, k in [64g, +64)
    const int c   = w & 1;                 // column half
    const int col = c * 64 + ln;           // 0..127
    const int jg  = s * SCOLS + col;       // global column
    const bool own       = (g >> 1) == s;  // k-slice owned by this block
    const bool is_leader = own && ((w & 2) == 0);   // waves 4s, 4s+1
    const bool self_h    = is_leader && (c == 0);   // wave 4s: h = own regs
    const bool use_l2    = (comm2 != nullptr);

    // one-time W slice load (coalesced across lanes), pinned
    float Wr[KPER];
    {
        const float* wp = W + (size_t)(g * KPER) * NREC + jg;
#pragma unroll
        for (int u = 0; u < KPER; ++u)
            Wr[u] = wp[(size_t)u * NREC];
    }
#pragma unroll
    for (int u = 0; u < KPER; ++u)
        asm volatile("" : "+v"(Wr[u]));

    float hj = 0.f;                        // leader lanes' own h_t[col]
    const size_t iobase = (size_t)b * T_STEPS * NREC + jg;
    const unsigned long long* cpoll  = comm  + (size_t)b * NREC + g * KPER + ln;
    const unsigned long long* cpoll2 = comm2 + (size_t)b * NREC + g * KPER + ln;
    unsigned long long* cwr  = comm  + (size_t)b * NREC + jg;
    unsigned long long* cwr2 = comm2 + (size_t)b * NREC + jg;

    // ---- prologue ----
    if (tid < 32) wflag[tid >> 4][tid & 15] = -1;   // < 0 = no contribution
    if (tid < 4)  hflag[tid >> 1][tid & 1] = 0;
    float inp = 0.f, nz = 0.f;                      // row t, for leader phase t
    if (is_leader) { inp = io[iobase]; nz = noise[iobase]; }
    __syncthreads();                                // the ONLY block barrier

    for (int t = 0; t < T_STEPS; ++t) {
        const int p = t & 1;

        // ---- acquire h_t[64g+ln] into a register ----
        float hval;
        if (t == 0) {
            hval = 0.f;
        } else if (self_h) {
            hval = hj;                              // own lanes ARE the slice
        } else if (own) {
            const int need = g & 1;                 // which col-half of h_own
            while (ld_lds_i32(&hflag[p][need]) < t) {}
            asm volatile("" ::: "memory");
            hval = h_own[p][need * 64 + ln];
        } else {
            const size_t po = (size_t)p * COMM_U64;
            unsigned long long v;
            if (use_l2) {
                v = ld_l2(cpoll2 + po);             // XCD-local fast path
                while ((int)(unsigned)(v >> 32) < t) {
                    v = ld_llc(cpoll + po);         // safety net
                    if ((int)(unsigned)(v >> 32) >= t) break;
                    v = ld_l2(cpoll2 + po);
                }
            } else {
                v = ld_llc(cpoll + po);
                while ((int)(unsigned)(v >> 32) < t)
                    v = ld_llc(cpoll + po);
            }
            hval = __uint_as_float((unsigned)(v & 0xffffffffu));
        }

        // ---- 64-long dot: readlane broadcast (VALU), W in regs ----
        float a0 = 0.f, a1 = 0.f;
#pragma unroll
        for (int u = 0; u < KPER; u += 2) {
            float h0 = __uint_as_float(
                __builtin_amdgcn_readlane(__float_as_uint(hval), u));
            float h1 = __uint_as_float(
                __builtin_amdgcn_readlane(__float_as_uint(hval), u + 1));
            a0 = fmaf(h0, Wr[u],     a0);
            a1 = fmaf(h1, Wr[u + 1], a1);
        }

        // ---- publish partial into this wave's own slot, then flag ----
        part[p][g][col] = a0 + a1;
        asm volatile("s_waitcnt lgkmcnt(0)" ::: "memory");
        if (ln == 0) wflag[p][w] = t;               // monotone step stamp

        // ---- leader: finish the step ----
        if (is_leader) {
            // issue row-(t+1) prefetch NOW; vmcnt wait lands at the register
            // copy below (after publish). Leaders poll only LDS -> pending
            // vmem never blocks a poll (r11 lesson, structural fix).
            float ninp = 0.f, nnz = 0.f;
            if (t + 1 < T_STEPS) {
                ninp = io[iobase + (size_t)(t + 1) * NREC];
                nnz  = noise[iobase + (size_t)(t + 1) * NREC];
            }
            // wait for all 16 wave flags (lanes replicate the 16 entries)
            for (;;) {
                int fv = ld_lds_i32(&wflag[p][ln & 15]);
                if (__all(fv >= t)) break;
            }
            asm volatile("" ::: "memory");
            float pre = inp + nz;
#pragma unroll
            for (int q = 0; q < NGRP; ++q)
                pre += part[p][q][col];             // 8 conflict-free reads
            float hnew = (1.f - ALPHA) * hj + ALPHA * fmaxf(pre, 0.f);
            hj = hnew;
            if (t + 1 < T_STEPS) {
                h_own[p ^ 1][col] = hnew;           // own-slice delivery
                asm volatile("s_waitcnt lgkmcnt(0)" ::: "memory");
                if (ln == 0) hflag[p ^ 1][c] = t + 1;
                unsigned long long pv =
                    ((unsigned long long)(unsigned)(t + 1) << 32) |
                    (unsigned long long)__float_as_uint(hnew);
                const size_t po = (size_t)((t + 1) & 1) * COMM_U64;
                if (use_l2) st_l2(cwr2 + po, pv);   // fast local publish
                st_llc(cwr + po, pv);               // guaranteed publish
            }
            io[iobase + (size_t)t * NREC] = hnew;   // trajectory row t
            inp = ninp; nz = nnz;                   // retire prefetch (vmcnt)
        }
    }
}

// ---------------------------------------------------------------------------
// Fallback (round-1 kernel) if ws_size is too small for comm buffers.
// ---------------------------------------------------------------------------
__global__ __launch_bounds__(1024) void rnn_kernel(
        const float* __restrict__ W,
        const float* __restrict__ noise,
        float* __restrict__ io) {
    __shared__ float h[NREC];
    __shared__ float part2[NREC];

    const int tid  = threadIdx.x;
    const int j    = tid & (NREC - 1);
    const int half = tid >> 9;
    const int b    = blockIdx.x;

    if (tid < NREC) h[tid] = 0.f;
    float hj = 0.f;
    __syncthreads();

    const int kb = half * 256;
    const float* wp = W + (size_t)kb * NREC + j;
    const size_t base = (size_t)b * T_STEPS * NREC + j;

    for (int t = 0; t < T_STEPS; ++t) {
        const size_t off = base + (size_t)t * NREC;
        float acc = (half == 0) ? (io[off] + noise[off]) : 0.f;
#pragma unroll
        for (int ku = 0; ku < 256; ku += 16) {
            float wv[16];
#pragma unroll
            for (int u = 0; u < 16; ++u) wv[u] = wp[(size_t)(ku + u) * NREC];
#pragma unroll
            for (int u = 0; u < 16; ++u) acc = fmaf(h[kb + ku + u], wv[u], acc);
        }
        if (half == 1) part2[j] = acc;
        __syncthreads();
        if (half == 0) {
            float pre  = acc + part2[j];
            float hnew = (1.f - ALPHA) * hj + ALPHA * fmaxf(pre, 0.f);
            io[off] = hnew;
            h[j] = hnew;
            hj = hnew;
        }
        __syncthreads();
    }
}

// ---------------------------------------------------------------------------
extern "C" void kernel_launch(void* const* d_in, const int* in_sizes, int n_in,
                              void* d_out, int out_size, void* d_ws, size_t ws_size,
                              hipStream_t stream) {
    const float* x       = (const float*)d_in[0];
    const float* w_in    = (const float*)d_in[1];
    const float* w_rec   = (const float*)d_in[2];
    const float* b_rec   = (const float*)d_in[3];
    const float* ei_mask = (const float*)d_in[4];
    const float* autapse = (const float*)d_in[5];
    const float* noise   = (const float*)d_in[6];
    float* out = (float*)d_out;

    char* ws = (char*)d_ws;
    float* W = (float*)(ws + WS_W_OFF);
    unsigned long long* comm  = (unsigned long long*)(ws + WS_COMM_OFF);
    unsigned long long* comm2 = (unsigned long long*)(ws + WS_COMM2_OFF);

    weff_kernel<<<dim3((NREC * NREC + 255) / 256), dim3(256), 0, stream>>>(
        w_rec, ei_mask, autapse, W);

    gemm_in_kernel<<<dim3(64000 / 32), dim3(1024), 0, stream>>>(
        x, w_in, b_rec, out);

    if (ws_size >= (size_t)WS_NEEDED_DUAL) {
        hipMemsetAsync(comm, 0, 2 * COMM_BYTES, stream);   // both slot arrays
        void* args[] = {(void*)&W, (void*)&noise, (void*)&out,
                        (void*)&comm, (void*)&comm2};
        hipLaunchCooperativeKernel(reinterpret_cast<void*>(rnn_coop),
                                   dim3(NBATCH * NSLICE), dim3(1024),
                                   args, 0, stream);
    } else if (ws_size >= (size_t)WS_NEEDED_LLC) {
        hipMemsetAsync(comm, 0, COMM_BYTES, stream);
        unsigned long long* nul = nullptr;
        void* args[] = {(void*)&W, (void*)&noise, (void*)&out,
                        (void*)&comm, (void*)&nul};
        hipLaunchCooperativeKernel(reinterpret_cast<void*>(rnn_coop),
                                   dim3(NBATCH * NSLICE), dim3(1024),
                                   args, 0, stream);
    } else {
        rnn_kernel<<<dim3(NBATCH), dim3(1024), 0, stream>>>(W, noise, out);
    }
}